// Round 1
// baseline (46.533 us; speedup 1.0000x reference)
//
#include <hip/hip_runtime.h>

// Problem constants
#define NJ       21
#define CH       3380      // floats per 64-split channel within a batch (5*26*26)
#define BSTRIDE  216320    // floats per batch (320*26*26 == 64*3380)
#define NCELL    3380      // W*H*DD
#define TPB_CELLS 845      // NCELL / 4 cells-per-thread

#define CA0 (1920.0f / 26.0f)
#define CA1 (1080.0f / 26.0f)
#define CA2 (1000.0f / 5.0f)
#define INVC0 0.15651764f   // 1/(e^2 - 1)

__device__ __forceinline__ float sigmoidf_(float x) {
    return 1.0f / (1.0f + __expf(-x));
}

__global__ __launch_bounds__(256) void hpo_main(
    const float* __restrict__ pred,
    const float* __restrict__ gt,
    float* __restrict__ partial)
{
    __shared__ float s_gs[NJ][3];   // gt * scale
    __shared__ float s_tv[NJ][3];   // target_uvd values at the GT cell
    __shared__ int   s_lin_sh;
    __shared__ float s_red[256];

    const int bid   = blockIdx.x;
    const int b     = bid >> 2;       // batch
    const int chunk = bid & 3;        // cell-chunk within batch
    const int tid   = threadIdx.x;

    const float* gtb = gt + b * (NJ * 3);

    if (tid < NJ * 3) {
        const int j = tid / 3;
        const int a = tid - 3 * j;
        const float scale_a = (a == 0) ? 1920.0f : ((a == 1) ? 1080.0f : 1000.0f);
        const float dim_a   = (a == 2) ? 5.0f : 26.0f;
        const int   dimi    = (a == 2) ? 5 : 26;
        const float gv = gtb[tid];
        s_gs[j][a] = gv * scale_a;
        // gidx comes from joint 0 (HAND_ROOT) only
        const float g0v = gtb[a];
        int gi = (int)(g0v * dim_a);
        gi = min(max(gi, 0), dimi - 1);
        s_tv[j][a] = gv * dim_a - (float)gi;
    }
    if (tid == 0) {
        int gi = min(max((int)(gtb[0] * 26.0f), 0), 25);
        int gj = min(max((int)(gtb[1] * 26.0f), 0), 25);
        int gk = min(max((int)(gtb[2] * 5.0f),  0), 4);
        s_lin_sh = 130 * gi + 5 * gj + gk;
    }
    __syncthreads();

    const int s_lin = s_lin_sh;
    const int t = chunk * 256 + tid;
    float acc = 0.0f;

    if (t < TPB_CELLS) {
        const int g0 = 4 * t;
        const float* base = pred + (size_t)b * BSTRIDE + g0;

        // per-cell constants: cell_coord * (scale/dim)
        float cb0[4], cb1[4], cb2[4];
#pragma unroll
        for (int k = 0; k < 4; ++k) {
            const int g   = g0 + k;
            const int w   = g / 130;
            const int rem = g - w * 130;
            const int h   = rem / 5;
            const int d   = rem - h * 5;
            cb0[k] = (float)w * CA0;
            cb1[k] = (float)h * CA1;
            cb2[k] = (float)d * CA2;
        }

        const int klin = s_lin - g0;   // in [0,4) iff this thread owns the GT cell

        float csum[4] = {0.0f, 0.0f, 0.0f, 0.0f};

        // ---- j = 0 (HAND_ROOT: sigmoid applied to inputs) ----
        {
            const float4 x = *(const float4*)(base);
            const float4 y = *(const float4*)(base + CH);
            const float4 z = *(const float4*)(base + 2 * CH);
            const float xv[4] = {sigmoidf_(x.x), sigmoidf_(x.y), sigmoidf_(x.z), sigmoidf_(x.w)};
            const float yv[4] = {sigmoidf_(y.x), sigmoidf_(y.y), sigmoidf_(y.z), sigmoidf_(y.w)};
            const float zv[4] = {sigmoidf_(z.x), sigmoidf_(z.y), sigmoidf_(z.z), sigmoidf_(z.w)};
            const float gs0 = s_gs[0][0], gs1 = s_gs[0][1], gs2 = s_gs[0][2];
#pragma unroll
            for (int k = 0; k < 4; ++k) {
                const float d0 = fmaf(xv[k], CA0, cb0[k] - gs0);
                const float d1 = fmaf(yv[k], CA1, cb1[k] - gs1);
                const float d2 = fmaf(zv[k], CA2, cb2[k] - gs2);
                const float dsq = fmaf(d0, d0, fmaf(d1, d1, fmaf(d2, d2, 1e-5f)));
                const float dist = sqrtf(dsq);
                const float c = (__expf(2.0f - dist * (2.0f / 75.0f)) - 1.0f) * INVC0;
                csum[k] += (dist < 75.0f) ? c : 0.0f;
            }
        }

        // ---- j = 1 .. 20 ----
        for (int j = 1; j < NJ; ++j) {
            const float* p = base + (size_t)(3 * j) * CH;
            const float4 x = *(const float4*)(p);
            const float4 y = *(const float4*)(p + CH);
            const float4 z = *(const float4*)(p + 2 * CH);
            const float xv[4] = {x.x, x.y, x.z, x.w};
            const float yv[4] = {y.x, y.y, y.z, y.w};
            const float zv[4] = {z.x, z.y, z.z, z.w};
            const float gs0 = s_gs[j][0], gs1 = s_gs[j][1], gs2 = s_gs[j][2];
#pragma unroll
            for (int k = 0; k < 4; ++k) {
                const float d0 = fmaf(xv[k], CA0, cb0[k] - gs0);
                const float d1 = fmaf(yv[k], CA1, cb1[k] - gs1);
                const float d2 = fmaf(zv[k], CA2, cb2[k] - gs2);
                const float dsq = fmaf(d0, d0, fmaf(d1, d1, fmaf(d2, d2, 1e-5f)));
                const float dist = sqrtf(dsq);
                const float c = (__expf(2.0f - dist * (2.0f / 75.0f)) - 1.0f) * INVC0;
                csum[k] += (dist < 75.0f) ? c : 0.0f;
            }
        }

        // ---- conf loss (channel 63) ----
        {
            const float4 wc = *(const float4*)(base + (size_t)63 * CH);
            const float wv[4] = {wc.x, wc.y, wc.z, wc.w};
#pragma unroll
            for (int k = 0; k < 4; ++k) {
                const float mc = csum[k] * (1.0f / 21.0f);
                const float pconf = sigmoidf_(wv[k]);
                const bool  il = (k == klin);
                const float cm2 = il ? 5.0f : ((mc > 0.6f) ? 0.0f : 0.1f);
                const float tc  = il ? mc : 0.0f;
                const float dd  = pconf - tc;
                acc += 0.5f * cm2 * dd * dd;
            }
        }

        // ---- u/v/d losses: only the GT cell contributes (onehot mask) ----
        if (klin >= 0 && klin < 4) {
            const float* p = pred + (size_t)b * BSTRIDE + s_lin;
#pragma unroll
            for (int j = 0; j < NJ; ++j) {
#pragma unroll
                for (int a = 0; a < 3; ++a) {
                    float v = p[(size_t)(3 * j + a) * CH];
                    if (j == 0) v = sigmoidf_(v);
                    const float d = v - s_tv[j][a];
                    acc += 0.5f * d * d;
                }
            }
        }
    }

    // ---- block reduction ----
    s_red[tid] = acc;
    __syncthreads();
    for (int s = 128; s > 0; s >>= 1) {
        if (tid < s) s_red[tid] += s_red[tid + s];
        __syncthreads();
    }
    if (tid == 0) partial[bid] = s_red[0];
}

__global__ __launch_bounds__(256) void hpo_reduce(
    const float* __restrict__ partial,
    float* __restrict__ out)
{
    __shared__ float s[256];
    const int tid = threadIdx.x;
    float a = partial[tid] + partial[tid + 256] + partial[tid + 512] + partial[tid + 768];
    s[tid] = a;
    __syncthreads();
    for (int st = 128; st > 0; st >>= 1) {
        if (tid < st) s[tid] += s[tid + st];
        __syncthreads();
    }
    if (tid == 0) out[0] = s[0];
}

extern "C" void kernel_launch(void* const* d_in, const int* in_sizes, int n_in,
                              void* d_out, int out_size, void* d_ws, size_t ws_size,
                              hipStream_t stream) {
    const float* pred = (const float*)d_in[0];
    const float* gt   = (const float*)d_in[1];
    float* out        = (float*)d_out;
    float* partial    = (float*)d_ws;   // 1024 floats

    hpo_main<<<1024, 256, 0, stream>>>(pred, gt, partial);
    hpo_reduce<<<1, 256, 0, stream>>>(partial, out);
}

// Round 2
// 43.116 us; speedup vs baseline: 1.0792x; 1.0792x over previous
//
#include <hip/hip_runtime.h>

// Problem constants
#define NJ       21
#define CH       3380      // floats per 64-split channel within a batch (26*26*5)
#define BSTRIDE  216320    // floats per batch (64*3380)
#define NCELL    3380      // W*H*DD
#define GROUPS   1690      // NCELL / 2 cells-per-thread
#define BLKS_PER_BATCH 7   // ceil(1690/256)

#define CA0 (1920.0f / 26.0f)
#define CA1 (1080.0f / 26.0f)
#define CA2 (1000.0f / 5.0f)
#define INVC0 0.15651764f   // 1/(e^2 - 1)

__device__ __forceinline__ float sigmoidf_(float x) {
    return 1.0f / (1.0f + __expf(-x));
}

__global__ __launch_bounds__(256, 7) void hpo_main(
    const float* __restrict__ pred,
    const float* __restrict__ gt,
    float* __restrict__ partial)
{
    __shared__ float s_gs[NJ][3];   // gt * scale
    __shared__ float s_tv[NJ][3];   // target_uvd values at the GT cell
    __shared__ int   s_lin_sh;
    __shared__ float s_red[256];

    const int bid   = blockIdx.x;
    const int b     = bid / BLKS_PER_BATCH;     // batch
    const int chunk = bid - b * BLKS_PER_BATCH; // cell-chunk within batch
    const int tid   = threadIdx.x;

    const float* gtb = gt + b * (NJ * 3);

    if (tid < NJ * 3) {
        const int j = tid / 3;
        const int a = tid - 3 * j;
        const float scale_a = (a == 0) ? 1920.0f : ((a == 1) ? 1080.0f : 1000.0f);
        const float dim_a   = (a == 2) ? 5.0f : 26.0f;
        const int   dimi    = (a == 2) ? 5 : 26;
        const float gv = gtb[tid];
        s_gs[j][a] = gv * scale_a;
        // gidx comes from joint 0 (HAND_ROOT) only
        const float g0v = gtb[a];
        int gi = (int)(g0v * dim_a);
        gi = min(max(gi, 0), dimi - 1);
        s_tv[j][a] = gv * dim_a - (float)gi;
    }
    if (tid == 0) {
        int gi = min(max((int)(gtb[0] * 26.0f), 0), 25);
        int gj = min(max((int)(gtb[1] * 26.0f), 0), 25);
        int gk = min(max((int)(gtb[2] * 5.0f),  0), 4);
        s_lin_sh = 130 * gi + 5 * gj + gk;
    }
    __syncthreads();

    const int s_lin = s_lin_sh;
    const int t = chunk * 256 + tid;
    float acc = 0.0f;

    if (t < GROUPS) {
        const int g0 = 2 * t;
        const float* base = pred + (size_t)b * BSTRIDE + g0;

        // per-cell constants: cell_coord * (scale/dim)
        float cb0[2], cb1[2], cb2[2];
#pragma unroll
        for (int k = 0; k < 2; ++k) {
            const int g   = g0 + k;
            const int w   = g / 130;
            const int rem = g - w * 130;
            const int h   = rem / 5;
            const int d   = rem - h * 5;
            cb0[k] = (float)w * CA0;
            cb1[k] = (float)h * CA1;
            cb2[k] = (float)d * CA2;
        }

        const int klin = s_lin - g0;   // in [0,2) iff this thread owns the GT cell

        float csum[2] = {0.0f, 0.0f};

        // ---- j = 0 (HAND_ROOT: sigmoid applied to inputs) ----
        {
            const float2 x = *(const float2*)(base);
            const float2 y = *(const float2*)(base + CH);
            const float2 z = *(const float2*)(base + 2 * CH);
            const float xv[2] = {sigmoidf_(x.x), sigmoidf_(x.y)};
            const float yv[2] = {sigmoidf_(y.x), sigmoidf_(y.y)};
            const float zv[2] = {sigmoidf_(z.x), sigmoidf_(z.y)};
            const float gs0 = s_gs[0][0], gs1 = s_gs[0][1], gs2 = s_gs[0][2];
#pragma unroll
            for (int k = 0; k < 2; ++k) {
                const float d0 = fmaf(xv[k], CA0, cb0[k] - gs0);
                const float d1 = fmaf(yv[k], CA1, cb1[k] - gs1);
                const float d2 = fmaf(zv[k], CA2, cb2[k] - gs2);
                const float dsq = fmaf(d0, d0, fmaf(d1, d1, fmaf(d2, d2, 1e-5f)));
                const float dist = sqrtf(dsq);
                const float c = (__expf(2.0f - dist * (2.0f / 75.0f)) - 1.0f) * INVC0;
                csum[k] += (dist < 75.0f) ? c : 0.0f;
            }
        }

        // ---- j = 1 .. 20 ----
        for (int j = 1; j < NJ; ++j) {
            const float* p = base + (size_t)(3 * j) * CH;
            const float2 x = *(const float2*)(p);
            const float2 y = *(const float2*)(p + CH);
            const float2 z = *(const float2*)(p + 2 * CH);
            const float xv[2] = {x.x, x.y};
            const float yv[2] = {y.x, y.y};
            const float zv[2] = {z.x, z.y};
            const float gs0 = s_gs[j][0], gs1 = s_gs[j][1], gs2 = s_gs[j][2];
#pragma unroll
            for (int k = 0; k < 2; ++k) {
                const float d0 = fmaf(xv[k], CA0, cb0[k] - gs0);
                const float d1 = fmaf(yv[k], CA1, cb1[k] - gs1);
                const float d2 = fmaf(zv[k], CA2, cb2[k] - gs2);
                const float dsq = fmaf(d0, d0, fmaf(d1, d1, fmaf(d2, d2, 1e-5f)));
                const float dist = sqrtf(dsq);
                const float c = (__expf(2.0f - dist * (2.0f / 75.0f)) - 1.0f) * INVC0;
                csum[k] += (dist < 75.0f) ? c : 0.0f;
            }
        }

        // ---- conf loss (channel 63) ----
        {
            const float2 wc = *(const float2*)(base + (size_t)63 * CH);
            const float wv[2] = {wc.x, wc.y};
#pragma unroll
            for (int k = 0; k < 2; ++k) {
                const float mc = csum[k] * (1.0f / 21.0f);
                const float pconf = sigmoidf_(wv[k]);
                const bool  il = (k == klin);
                const float cm2 = il ? 5.0f : ((mc > 0.6f) ? 0.0f : 0.1f);
                const float tc  = il ? mc : 0.0f;
                const float dd  = pconf - tc;
                acc += 0.5f * cm2 * dd * dd;
            }
        }

        // ---- u/v/d losses: only the GT cell contributes (onehot mask) ----
        if ((unsigned)klin < 2u) {
            const float* p = pred + (size_t)b * BSTRIDE + s_lin;
#pragma unroll
            for (int j = 0; j < NJ; ++j) {
#pragma unroll
                for (int a = 0; a < 3; ++a) {
                    float v = p[(size_t)(3 * j + a) * CH];
                    if (j == 0) v = sigmoidf_(v);
                    const float d = v - s_tv[j][a];
                    acc += 0.5f * d * d;
                }
            }
        }
    }

    // ---- block reduction ----
    s_red[tid] = acc;
    __syncthreads();
    for (int s = 128; s > 0; s >>= 1) {
        if (tid < s) s_red[tid] += s_red[tid + s];
        __syncthreads();
    }
    if (tid == 0) partial[bid] = s_red[0];
}

__global__ __launch_bounds__(256) void hpo_reduce(
    const float* __restrict__ partial,
    float* __restrict__ out)
{
    __shared__ float s[256];
    const int tid = threadIdx.x;
    float a = 0.0f;
#pragma unroll
    for (int i = 0; i < BLKS_PER_BATCH; ++i)   // 1792 = 7 * 256
        a += partial[tid + 256 * i];
    s[tid] = a;
    __syncthreads();
    for (int st = 128; st > 0; st >>= 1) {
        if (tid < st) s[tid] += s[tid + st];
        __syncthreads();
    }
    if (tid == 0) out[0] = s[0];
}

extern "C" void kernel_launch(void* const* d_in, const int* in_sizes, int n_in,
                              void* d_out, int out_size, void* d_ws, size_t ws_size,
                              hipStream_t stream) {
    const float* pred = (const float*)d_in[0];
    const float* gt   = (const float*)d_in[1];
    float* out        = (float*)d_out;
    float* partial    = (float*)d_ws;   // 1792 floats

    hpo_main<<<256 * BLKS_PER_BATCH, 256, 0, stream>>>(pred, gt, partial);
    hpo_reduce<<<1, 256, 0, stream>>>(partial, out);
}